// Round 2
// baseline (613.848 us; speedup 1.0000x reference)
//
#include <hip/hip_runtime.h>
#include <hip/hip_bf16.h>

namespace {

constexpr int kB = 32;
constexpr int kS = 2048;
constexpr int kD = 1024;
constexpr int kU = 1024;
constexpr int BM = 128;
constexpr int BN = 128;
constexpr int BK = 64;

typedef __attribute__((ext_vector_type(8))) short bf16x8;
typedef __attribute__((ext_vector_type(4))) float f32x4;

__device__ __forceinline__ unsigned short f2bf(float x) {
  union { __hip_bfloat16 h; unsigned short u; } c;
  c.h = __float2bfloat16(x);
  return c.u;
}

// tanh(x) = 1 - 2/(exp(2x)+1); saturates correctly at +-large x.
__device__ __forceinline__ float tanh_fast(float x) {
  float e = __expf(2.0f * x);
  return 1.0f - 2.0f * __builtin_amdgcn_rcpf(e + 1.0f);
}

// h2[b][u] = Wh_b[u] + Ws_b[u] + Wc_b[u] + sum_d dec[b][d] * Wh_w[d][u]
__global__ __launch_bounds__(256) void h2_kernel(
    const float* __restrict__ dec, const float* __restrict__ Whw,
    const float* __restrict__ Whb, const float* __restrict__ Wsb,
    const float* __restrict__ Wcb, float* __restrict__ h2) {
  const int b = blockIdx.y;
  const int u = blockIdx.x * 256 + threadIdx.x;
  float acc = Whb[u] + Wsb[u] + Wcb[u];
  const float* dh = dec + b * kD;
  #pragma unroll 8
  for (int d = 0; d < kD; ++d) acc += dh[d] * Whw[(size_t)d * kU + u];
  h2[b * kU + u] = acc;
}

// WsT[u][d] = bf16(Ws_w[d][u])  (B^T layout for the MFMA B-operand)
__global__ __launch_bounds__(256) void tpose_kernel(
    const float* __restrict__ W, unsigned short* __restrict__ out) {
  __shared__ float tile[32][33];
  const int u0 = blockIdx.x * 32, d0 = blockIdx.y * 32;
  const int tx = threadIdx.x, ty = threadIdx.y;  // 32 x 8
  #pragma unroll
  for (int i = 0; i < 4; ++i)
    tile[ty + i * 8][tx] = W[(size_t)(d0 + ty + i * 8) * kU + u0 + tx];
  __syncthreads();
  #pragma unroll
  for (int i = 0; i < 4; ++i)
    out[(size_t)(u0 + ty + i * 8) * kD + d0 + tx] = f2bf(tile[tx][ty + i * 8]);
}

// Fused: score[r] += sum_u tanh( (enc@Ws)[r,u] + h2[b,u] + pc[r]*Wcw[u] ) * Vw[u]
// 128x128 tile, BK=64, 4 waves (each 64x64 via 4x4 frags of 16x16x32 bf16 MFMA).
// fp32 -> bf16 conversion fused into reg-staged LDS writes; XOR-swizzled LDS.
__global__ __launch_bounds__(256, 2) void score_gemm_kernel(
    const float* __restrict__ enc, const unsigned short* __restrict__ WsT,
    const float* __restrict__ h2, const float* __restrict__ pc,
    const float* __restrict__ Wcw, const float* __restrict__ Vw,
    float* __restrict__ score) {
  __shared__ __attribute__((aligned(16))) unsigned char smA[BM * BK * 2];  // 16 KiB
  __shared__ __attribute__((aligned(16))) unsigned char smB[BN * BK * 2];  // 16 KiB

  const int tid = threadIdx.x;
  const int lane = tid & 63;
  const int wid = tid >> 6;
  const int wr = wid >> 1, wc = wid & 1;
  const int mtile = blockIdx.x >> 3, ntile = blockIdx.x & 7;
  const int r0 = mtile * BM, n0 = ntile * BN;

  f32x4 acc[4][4];
  #pragma unroll
  for (int i = 0; i < 4; ++i)
    #pragma unroll
    for (int j = 0; j < 4; ++j) acc[i][j] = (f32x4){0.f, 0.f, 0.f, 0.f};

  const int kqA = tid & 15;   // float4-column within the 64-wide K slab
  const int rowA = tid >> 4;  // base row (+16 per iter), in [0,16)
  const int kcB = tid & 7;    // 16B chunk within the 128B row (8 chunks)
  const int nB = tid >> 3;    // base n (+32 per iter), in [0,32)

  float4 aReg[8];
  uint4 bReg[4];

  #pragma unroll
  for (int i = 0; i < 8; ++i)
    aReg[i] = *(const float4*)(enc + (size_t)(r0 + rowA + 16 * i) * kD + kqA * 4);
  #pragma unroll
  for (int i = 0; i < 4; ++i)
    bReg[i] = *(const uint4*)(WsT + (size_t)(n0 + nB + 32 * i) * kD + kcB * 8);

  const int lr = lane & 15, lq = lane >> 4;

  for (int k0 = 0; k0 < kD; k0 += BK) {
    // regs -> LDS (cvt to bf16 for A), XOR-swizzled within 128B rows
    #pragma unroll
    for (int i = 0; i < 8; ++i) {
      const int row = rowA + 16 * i;
      uint2 p;
      p.x = (unsigned)f2bf(aReg[i].x) | ((unsigned)f2bf(aReg[i].y) << 16);
      p.y = (unsigned)f2bf(aReg[i].z) | ((unsigned)f2bf(aReg[i].w) << 16);
      *(uint2*)(smA + row * 128 + ((kqA * 8) ^ ((row & 7) << 4))) = p;
    }
    #pragma unroll
    for (int i = 0; i < 4; ++i) {
      const int n = nB + 32 * i;
      *(uint4*)(smB + n * 128 + ((kcB * 16) ^ ((n & 7) << 4))) = bReg[i];
    }
    __syncthreads();
    if (k0 + BK < kD) {  // prefetch next K slab into regs (overlaps compute)
      const int kn = k0 + BK;
      #pragma unroll
      for (int i = 0; i < 8; ++i)
        aReg[i] = *(const float4*)(enc + (size_t)(r0 + rowA + 16 * i) * kD + kn + kqA * 4);
      #pragma unroll
      for (int i = 0; i < 4; ++i)
        bReg[i] = *(const uint4*)(WsT + (size_t)(n0 + nB + 32 * i) * kD + kn + kcB * 8);
    }
    #pragma unroll
    for (int ks = 0; ks < 2; ++ks) {
      const int kb = ks * 64 + lq * 16;  // byte offset: 32-elem half + 8-elem lane slice
      bf16x8 af[4], bfr[4];
      #pragma unroll
      for (int fm = 0; fm < 4; ++fm) {
        const int row = wr * 64 + fm * 16 + lr;
        af[fm] = *(const bf16x8*)(smA + row * 128 + (kb ^ ((row & 7) << 4)));
      }
      #pragma unroll
      for (int fn = 0; fn < 4; ++fn) {
        const int n = wc * 64 + fn * 16 + lr;
        bfr[fn] = *(const bf16x8*)(smB + n * 128 + (kb ^ ((n & 7) << 4)));
      }
      #pragma unroll
      for (int fm = 0; fm < 4; ++fm)
        #pragma unroll
        for (int fn = 0; fn < 4; ++fn)
          acc[fm][fn] =
              __builtin_amdgcn_mfma_f32_16x16x32_bf16(af[fm], bfr[fn], acc[fm][fn], 0, 0, 0);
    }
    __syncthreads();
  }

  // Epilogue: tanh + dot with Vw over this block's 128 columns, atomicAdd row partials.
  const int bidx = r0 >> 11;  // whole tile lies in one batch row-block (2048 % 128 == 0)
  float hv[4], wv[4], vv[4];
  #pragma unroll
  for (int fn = 0; fn < 4; ++fn) {
    const int u = n0 + wc * 64 + fn * 16 + lr;
    hv[fn] = h2[bidx * kU + u];
    wv[fn] = Wcw[u];
    vv[fn] = Vw[u];
  }
  #pragma unroll
  for (int fm = 0; fm < 4; ++fm) {
    #pragma unroll
    for (int j = 0; j < 4; ++j) {
      const int r = r0 + wr * 64 + fm * 16 + lq * 4 + j;  // C row = (lane>>4)*4 + reg
      const float pcv = pc[r];
      float partial = 0.f;
      #pragma unroll
      for (int fn = 0; fn < 4; ++fn) {
        const float feat = acc[fm][fn][j] + hv[fn] + pcv * wv[fn];
        partial += tanh_fast(feat) * vv[fn];
      }
      partial += __shfl_xor(partial, 1);
      partial += __shfl_xor(partial, 2);
      partial += __shfl_xor(partial, 4);
      partial += __shfl_xor(partial, 8);
      if (lr == 0) atomicAdd(&score[r], partial);
    }
  }
}

// Per-b softmax over S, plus coverage = attn + prev_coverage. (V_b is softmax-invariant.)
__global__ __launch_bounds__(256) void softmax_kernel(
    const float* __restrict__ score, const float* __restrict__ pc,
    float* __restrict__ attn, float* __restrict__ cov) {
  const int b = blockIdx.x, tid = threadIdx.x;
  const int lane = tid & 63, wid = tid >> 6;
  const float* s = score + (size_t)b * kS;
  float v[8];
  *(float4*)(v) = *(const float4*)(s + tid * 8);
  *(float4*)(v + 4) = *(const float4*)(s + tid * 8 + 4);
  float m = v[0];
  #pragma unroll
  for (int i = 1; i < 8; ++i) m = fmaxf(m, v[i]);
  #pragma unroll
  for (int msk = 1; msk < 64; msk <<= 1) m = fmaxf(m, __shfl_xor(m, msk));
  __shared__ float redm[4], reds[4];
  if (lane == 0) redm[wid] = m;
  __syncthreads();
  m = fmaxf(fmaxf(redm[0], redm[1]), fmaxf(redm[2], redm[3]));
  float e[8], sum = 0.f;
  #pragma unroll
  for (int i = 0; i < 8; ++i) { e[i] = __expf(v[i] - m); sum += e[i]; }
  #pragma unroll
  for (int msk = 1; msk < 64; msk <<= 1) sum += __shfl_xor(sum, msk);
  if (lane == 0) reds[wid] = sum;
  __syncthreads();
  sum = reds[0] + reds[1] + reds[2] + reds[3];
  const float inv = 1.0f / sum;
  float pv[8], a[8], c[8];
  const float* p = pc + (size_t)b * kS + tid * 8;
  *(float4*)(pv) = *(const float4*)(p);
  *(float4*)(pv + 4) = *(const float4*)(p + 4);
  #pragma unroll
  for (int i = 0; i < 8; ++i) { a[i] = e[i] * inv; c[i] = a[i] + pv[i]; }
  *(float4*)(attn + (size_t)b * kS + tid * 8) = *(float4*)(a);
  *(float4*)(attn + (size_t)b * kS + tid * 8 + 4) = *(float4*)(a + 4);
  *(float4*)(cov + (size_t)b * kS + tid * 8) = *(float4*)(c);
  *(float4*)(cov + (size_t)b * kS + tid * 8 + 4) = *(float4*)(c + 4);
}

// context[b][d] = sum_s attn[b][s] * enc[b][s][d]   (S split across blocks, atomics)
__global__ __launch_bounds__(256) void context_kernel(
    const float* __restrict__ enc, const float* __restrict__ attn,
    float* __restrict__ ctx) {
  const int b = blockIdx.z;
  const int s0 = blockIdx.y * 256;
  const int d = blockIdx.x * 256 + threadIdx.x;
  const float* e = enc + ((size_t)b * kS + s0) * kD + d;
  const float* a = attn + (size_t)b * kS + s0;
  float acc = 0.f;
  #pragma unroll 8
  for (int s = 0; s < 256; ++s) acc += a[s] * e[(size_t)s * kD];
  atomicAdd(&ctx[b * kD + d], acc);
}

}  // namespace

extern "C" void kernel_launch(void* const* d_in, const int* in_sizes, int n_in,
                              void* d_out, int out_size, void* d_ws, size_t ws_size,
                              hipStream_t stream) {
  (void)in_sizes; (void)n_in; (void)out_size; (void)ws_size;
  const float* dec = (const float*)d_in[0];
  const float* enc = (const float*)d_in[1];
  // d_in[2] enc_pad_mask: unused (all ones). d_in[3] use_coverage: True in this problem.
  const float* pc  = (const float*)d_in[4];
  const float* Wsw = (const float*)d_in[5];
  const float* Wsb = (const float*)d_in[6];
  const float* Whw = (const float*)d_in[7];
  const float* Whb = (const float*)d_in[8];
  const float* Wcw = (const float*)d_in[9];
  const float* Wcb = (const float*)d_in[10];
  const float* Vw  = (const float*)d_in[11];
  // d_in[12] V_b: constant shift before softmax -> no effect on any output.

  float* ctx  = (float*)d_out;             // [B, D]
  float* attn = (float*)d_out + kB * kD;   // [B, S]
  float* cov  = attn + kB * kS;            // [B, S, 1]

  unsigned char* ws = (unsigned char*)d_ws;
  unsigned short* WsT = (unsigned short*)ws;                        // 2 MiB  bf16 [U][D]
  float* h2    = (float*)(ws + (size_t)2 * 1024 * 1024);            // 128 KiB
  float* score = (float*)(ws + (size_t)2 * 1024 * 1024 + 131072);   // 256 KiB

  hipMemsetAsync(score, 0, kB * kS * sizeof(float), stream);
  hipMemsetAsync(ctx, 0, kB * kD * sizeof(float), stream);

  h2_kernel<<<dim3(kU / 256, kB), 256, 0, stream>>>(dec, Whw, Whb, Wsb, Wcb, h2);
  tpose_kernel<<<dim3(kU / 32, kD / 32), dim3(32, 8), 0, stream>>>(Wsw, WsT);
  score_gemm_kernel<<<dim3((kB * kS / BM) * (kU / BN)), 256, 0, stream>>>(
      enc, WsT, h2, pc, Wcw, Vw, score);
  softmax_kernel<<<dim3(kB), 256, 0, stream>>>(score, pc, attn, cov);
  context_kernel<<<dim3(kD / 256, kS / 256, kB), 256, 0, stream>>>(enc, attn, ctx);
}

// Round 3
// 347.035 us; speedup vs baseline: 1.7688x; 1.7688x over previous
//
#include <hip/hip_runtime.h>
#include <hip/hip_bf16.h>

namespace {

constexpr int kB = 32;
constexpr int kS = 2048;
constexpr int kD = 1024;
constexpr int kU = 1024;
constexpr int BM = 128;
constexpr int BN = 128;
constexpr int BK = 64;
constexpr int kMT = (kB * kS) / BM;  // 512 m-tiles
constexpr int kNT = kU / BN;         // 8 n-tiles
constexpr int kKS = kD / BK;         // 16 k-slabs
constexpr size_t kChunk = (size_t)BM * BK * 2;  // 16 KiB per (tile, kslab)

typedef __attribute__((ext_vector_type(8))) short bf16x8;
typedef __attribute__((ext_vector_type(4))) float f32x4;

__device__ __forceinline__ unsigned short f2bf(float x) {
  union { __hip_bfloat16 h; unsigned short u; } c;
  c.h = __float2bfloat16(x);
  return c.u;
}

__device__ __forceinline__ float tanh_fast(float x) {
  float e = __expf(2.0f * x);
  return 1.0f - 2.0f * __builtin_amdgcn_rcpf(e + 1.0f);
}

__device__ __forceinline__ void gload16(const void* g, void* l) {
  __builtin_amdgcn_global_load_lds(
      (const __attribute__((address_space(1))) void*)g,
      (__attribute__((address_space(3))) void*)l, 16, 0, 0);
}

// ---------------- shared kernels ----------------

// h2[b][u] = Wh_b[u] + Ws_b[u] + Wc_b[u] + sum_d dec[b][d] * Wh_w[d][u]
__global__ __launch_bounds__(256) void h2_kernel(
    const float* __restrict__ dec, const float* __restrict__ Whw,
    const float* __restrict__ Whb, const float* __restrict__ Wsb,
    const float* __restrict__ Wcb, float* __restrict__ h2) {
  const int b = blockIdx.y;
  const int u = blockIdx.x * 256 + threadIdx.x;
  float acc = Whb[u] + Wsb[u] + Wcb[u];
  const float* dh = dec + b * kD;
  #pragma unroll 8
  for (int d = 0; d < kD; ++d) acc += dh[d] * Whw[(size_t)d * kU + u];
  h2[b * kU + u] = acc;
}

// context[b][d] = sum_s attn[b][s] * enc[b][s][d]
__global__ __launch_bounds__(256) void context_kernel(
    const float* __restrict__ enc, const float* __restrict__ attn,
    float* __restrict__ ctx) {
  const int b = blockIdx.z;
  const int s0 = blockIdx.y * 256;
  const int d = blockIdx.x * 256 + threadIdx.x;
  const float* e = enc + ((size_t)b * kS + s0) * kD + d;
  const float* a = attn + (size_t)b * kS + s0;
  float acc = 0.f;
  #pragma unroll 8
  for (int s = 0; s < 256; ++s) acc += a[s] * e[(size_t)s * kD];
  atomicAdd(&ctx[b * kD + d], acc);
}

// ---------------- fast path: tiled bf16 operands + global_load_lds ----------------

// enc fp32 [65536][1024] -> encT bf16 in GEMM-ready layout:
// chunk (mtile, kslab) of 16 KiB; within chunk, row-major 128 rows x 128 B with
// 16B-granular XOR swizzle: byte = row*128 + (((c>>3)<<4) ^ ((row&7)<<4)) + (c&7)*2.
__global__ __launch_bounds__(256) void convA_kernel(
    const float* __restrict__ enc, unsigned char* __restrict__ encT) {
  const size_t e = ((size_t)blockIdx.x * 256 + threadIdx.x) * 8;
  const int r = (int)(e >> 10), d0 = (int)(e & 1023);
  float4 v0 = *(const float4*)(enc + e);
  float4 v1 = *(const float4*)(enc + e + 4);
  uint4 p;
  p.x = (unsigned)f2bf(v0.x) | ((unsigned)f2bf(v0.y) << 16);
  p.y = (unsigned)f2bf(v0.z) | ((unsigned)f2bf(v0.w) << 16);
  p.z = (unsigned)f2bf(v1.x) | ((unsigned)f2bf(v1.y) << 16);
  p.w = (unsigned)f2bf(v1.z) | ((unsigned)f2bf(v1.w) << 16);
  const int mt = r >> 7, row = r & 127, ks = d0 >> 6, c = d0 & 63;  // c multiple of 8
  unsigned char* dst = encT + ((size_t)mt * kKS + ks) * kChunk + row * 128 +
                       (((c >> 3) << 4) ^ ((row & 7) << 4));
  *(uint4*)dst = p;
}

// Ws_w fp32 [D][U] -> bf16 B^T in the same tiled+swizzled layout (rows = u).
__global__ __launch_bounds__(256) void tpose2_kernel(
    const float* __restrict__ W, unsigned char* __restrict__ Bt) {
  __shared__ float tile[32][33];
  const int u0 = blockIdx.x * 32, d0 = blockIdx.y * 32;
  const int tx = threadIdx.x, ty = threadIdx.y;  // 32 x 8
  #pragma unroll
  for (int i = 0; i < 4; ++i)
    tile[ty + i * 8][tx] = W[(size_t)(d0 + ty + i * 8) * kU + u0 + tx];
  __syncthreads();
  #pragma unroll
  for (int i = 0; i < 4; ++i) {
    const int u = u0 + ty + i * 8, d = d0 + tx;
    const int nt = u >> 7, n = u & 127, ks = d >> 6, c = d & 63;
    *(unsigned short*)(Bt + ((size_t)nt * kKS + ks) * kChunk + n * 128 +
                       ((((c >> 3) << 4) ^ ((n & 7) << 4)) + (c & 7) * 2)) =
        f2bf(tile[tx][ty + i * 8]);
  }
}

// Fused score GEMM, m97 structure: global_load_lds(16B) -> barrier -> MFMA -> barrier.
// XCD-swizzled work mapping; partial scores to scorep[16][65536] (no atomics).
__global__ __launch_bounds__(256, 4) void score_gemm2_kernel(
    const unsigned char* __restrict__ encT, const unsigned char* __restrict__ Bt,
    const float* __restrict__ h2, const float* __restrict__ pc,
    const float* __restrict__ Wcw, const float* __restrict__ Vw,
    float* __restrict__ scorep) {
  __shared__ __attribute__((aligned(16))) unsigned char smA[kChunk];  // 16 KiB
  __shared__ __attribute__((aligned(16))) unsigned char smB[kChunk];  // 16 KiB

  const int tid = threadIdx.x;
  const int lane = tid & 63;
  const int w = tid >> 6;
  const int wr = w >> 1, wc = w & 1;

  // XCD-aware bijective swizzle: nwg=4096, 8 XCDs -> XCD x owns works [512x, 512x+512):
  // consecutive works = 8 ntiles of one mtile, then next mtile -> A panel fetched once/XCD,
  // B (2 MiB) L2-resident.
  const int work = (blockIdx.x & 7) * (kMT * kNT / 8) + (blockIdx.x >> 3);
  const int mtile = work >> 3, ntile = work & 7;
  const int r0 = mtile * BM, n0 = ntile * BN;

  const unsigned char* Ab = encT + (size_t)mtile * kKS * kChunk + (size_t)w * 4096 + lane * 16;
  const unsigned char* Bb = Bt + (size_t)ntile * kKS * kChunk + (size_t)w * 4096 + lane * 16;

  f32x4 acc[4][4];
  #pragma unroll
  for (int i = 0; i < 4; ++i)
    #pragma unroll
    for (int j = 0; j < 4; ++j) acc[i][j] = (f32x4){0.f, 0.f, 0.f, 0.f};

  const int lr = lane & 15, lq = lane >> 4;

  for (int ks = 0; ks < kKS; ++ks) {
    // stage 16 KiB A + 16 KiB B; wave w copies bytes [w*4K, w*4K+4K) of each chunk
    #pragma unroll
    for (int i = 0; i < 4; ++i) {
      gload16(Ab + (size_t)ks * kChunk + i * 1024, smA + w * 4096 + i * 1024);
      gload16(Bb + (size_t)ks * kChunk + i * 1024, smB + w * 4096 + i * 1024);
    }
    __syncthreads();  // compiler drains vmcnt before s_barrier -> LDS ready
    #pragma unroll
    for (int k2 = 0; k2 < 2; ++k2) {
      const int kb = k2 * 64 + lq * 16;
      bf16x8 af[4], bfr[4];
      #pragma unroll
      for (int fm = 0; fm < 4; ++fm) {
        const int row = wr * 64 + fm * 16 + lr;
        af[fm] = *(const bf16x8*)(smA + row * 128 + (kb ^ ((row & 7) << 4)));
      }
      #pragma unroll
      for (int fn = 0; fn < 4; ++fn) {
        const int n = wc * 64 + fn * 16 + lr;
        bfr[fn] = *(const bf16x8*)(smB + n * 128 + (kb ^ ((n & 7) << 4)));
      }
      #pragma unroll
      for (int fm = 0; fm < 4; ++fm)
        #pragma unroll
        for (int fn = 0; fn < 4; ++fn)
          acc[fm][fn] =
              __builtin_amdgcn_mfma_f32_16x16x32_bf16(af[fm], bfr[fn], acc[fm][fn], 0, 0, 0);
    }
    __syncthreads();  // all waves done reading before next overwrite
  }

  // Epilogue: tanh + dot(Vw) over this block's 128 u-columns -> partial-score plane.
  const int bidx = r0 >> 11;
  float hv[4], wv[4], vv[4];
  #pragma unroll
  for (int fn = 0; fn < 4; ++fn) {
    const int u = n0 + wc * 64 + fn * 16 + lr;
    hv[fn] = h2[bidx * kU + u];
    wv[fn] = Wcw[u];
    vv[fn] = Vw[u];
  }
  float* plane = scorep + (size_t)((ntile << 1) | wc) * (kB * kS);
  #pragma unroll
  for (int fm = 0; fm < 4; ++fm) {
    #pragma unroll
    for (int j = 0; j < 4; ++j) {
      const int r = r0 + wr * 64 + fm * 16 + lq * 4 + j;  // C row = (lane>>4)*4 + reg
      const float pcv = pc[r];
      float partial = 0.f;
      #pragma unroll
      for (int fn = 0; fn < 4; ++fn) {
        const float feat = acc[fm][fn][j] + hv[fn] + pcv * wv[fn];
        partial += tanh_fast(feat) * vv[fn];
      }
      partial += __shfl_xor(partial, 1);
      partial += __shfl_xor(partial, 2);
      partial += __shfl_xor(partial, 4);
      partial += __shfl_xor(partial, 8);
      if (lr == 0) plane[r] = partial;
    }
  }
}

// softmax over S per b, summing the 16 partial-score planes; cov = attn + pc.
__global__ __launch_bounds__(256) void softmax2_kernel(
    const float* __restrict__ scorep, const float* __restrict__ pc,
    float* __restrict__ attn, float* __restrict__ cov) {
  const int b = blockIdx.x, tid = threadIdx.x;
  const int lane = tid & 63, wid = tid >> 6;
  const size_t base = (size_t)b * kS + tid * 8;
  float v[8] = {0.f, 0.f, 0.f, 0.f, 0.f, 0.f, 0.f, 0.f};
  #pragma unroll
  for (int p = 0; p < 16; ++p) {
    const float* s = scorep + (size_t)p * (kB * kS) + base;
    float4 a = *(const float4*)(s);
    float4 c = *(const float4*)(s + 4);
    v[0] += a.x; v[1] += a.y; v[2] += a.z; v[3] += a.w;
    v[4] += c.x; v[5] += c.y; v[6] += c.z; v[7] += c.w;
  }
  float m = v[0];
  #pragma unroll
  for (int i = 1; i < 8; ++i) m = fmaxf(m, v[i]);
  #pragma unroll
  for (int msk = 1; msk < 64; msk <<= 1) m = fmaxf(m, __shfl_xor(m, msk));
  __shared__ float redm[4], reds[4];
  if (lane == 0) redm[wid] = m;
  __syncthreads();
  m = fmaxf(fmaxf(redm[0], redm[1]), fmaxf(redm[2], redm[3]));
  float e[8], sum = 0.f;
  #pragma unroll
  for (int i = 0; i < 8; ++i) { e[i] = __expf(v[i] - m); sum += e[i]; }
  #pragma unroll
  for (int msk = 1; msk < 64; msk <<= 1) sum += __shfl_xor(sum, msk);
  if (lane == 0) reds[wid] = sum;
  __syncthreads();
  sum = reds[0] + reds[1] + reds[2] + reds[3];
  const float inv = 1.0f / sum;
  float pv[8], a[8], c[8];
  const float* p = pc + base;
  *(float4*)(pv) = *(const float4*)(p);
  *(float4*)(pv + 4) = *(const float4*)(p + 4);
  #pragma unroll
  for (int i = 0; i < 8; ++i) { a[i] = e[i] * inv; c[i] = a[i] + pv[i]; }
  *(float4*)(attn + base) = *(float4*)(a);
  *(float4*)(attn + base + 4) = *(float4*)(a + 4);
  *(float4*)(cov + base) = *(float4*)(c);
  *(float4*)(cov + base + 4) = *(float4*)(c + 4);
}

// ---------------- fallback path (round-2 proven kernels, small ws) ----------------

__global__ __launch_bounds__(256) void tpose_fb_kernel(
    const float* __restrict__ W, unsigned short* __restrict__ out) {
  __shared__ float tile[32][33];
  const int u0 = blockIdx.x * 32, d0 = blockIdx.y * 32;
  const int tx = threadIdx.x, ty = threadIdx.y;
  #pragma unroll
  for (int i = 0; i < 4; ++i)
    tile[ty + i * 8][tx] = W[(size_t)(d0 + ty + i * 8) * kU + u0 + tx];
  __syncthreads();
  #pragma unroll
  for (int i = 0; i < 4; ++i)
    out[(size_t)(u0 + ty + i * 8) * kD + d0 + tx] = f2bf(tile[tx][ty + i * 8]);
}

__global__ __launch_bounds__(256, 2) void score_gemm_fb_kernel(
    const float* __restrict__ enc, const unsigned short* __restrict__ WsT,
    const float* __restrict__ h2, const float* __restrict__ pc,
    const float* __restrict__ Wcw, const float* __restrict__ Vw,
    float* __restrict__ score) {
  __shared__ __attribute__((aligned(16))) unsigned char smA[BM * BK * 2];
  __shared__ __attribute__((aligned(16))) unsigned char smB[BN * BK * 2];
  const int tid = threadIdx.x;
  const int lane = tid & 63;
  const int wid = tid >> 6;
  const int wr = wid >> 1, wc = wid & 1;
  const int mtile = blockIdx.x >> 3, ntile = blockIdx.x & 7;
  const int r0 = mtile * BM, n0 = ntile * BN;
  f32x4 acc[4][4];
  #pragma unroll
  for (int i = 0; i < 4; ++i)
    #pragma unroll
    for (int j = 0; j < 4; ++j) acc[i][j] = (f32x4){0.f, 0.f, 0.f, 0.f};
  const int kqA = tid & 15;
  const int rowA = tid >> 4;
  const int kcB = tid & 7;
  const int nB = tid >> 3;
  float4 aReg[8];
  uint4 bReg[4];
  #pragma unroll
  for (int i = 0; i < 8; ++i)
    aReg[i] = *(const float4*)(enc + (size_t)(r0 + rowA + 16 * i) * kD + kqA * 4);
  #pragma unroll
  for (int i = 0; i < 4; ++i)
    bReg[i] = *(const uint4*)(WsT + (size_t)(n0 + nB + 32 * i) * kD + kcB * 8);
  const int lr = lane & 15, lq = lane >> 4;
  for (int k0 = 0; k0 < kD; k0 += BK) {
    #pragma unroll
    for (int i = 0; i < 8; ++i) {
      const int row = rowA + 16 * i;
      uint2 p;
      p.x = (unsigned)f2bf(aReg[i].x) | ((unsigned)f2bf(aReg[i].y) << 16);
      p.y = (unsigned)f2bf(aReg[i].z) | ((unsigned)f2bf(aReg[i].w) << 16);
      *(uint2*)(smA + row * 128 + ((kqA * 8) ^ ((row & 7) << 4))) = p;
    }
    #pragma unroll
    for (int i = 0; i < 4; ++i) {
      const int n = nB + 32 * i;
      *(uint4*)(smB + n * 128 + ((kcB * 16) ^ ((n & 7) << 4))) = bReg[i];
    }
    __syncthreads();
    if (k0 + BK < kD) {
      const int kn = k0 + BK;
      #pragma unroll
      for (int i = 0; i < 8; ++i)
        aReg[i] = *(const float4*)(enc + (size_t)(r0 + rowA + 16 * i) * kD + kn + kqA * 4);
      #pragma unroll
      for (int i = 0; i < 4; ++i)
        bReg[i] = *(const uint4*)(WsT + (size_t)(n0 + nB + 32 * i) * kD + kn + kcB * 8);
    }
    #pragma unroll
    for (int ks = 0; ks < 2; ++ks) {
      const int kb = ks * 64 + lq * 16;
      bf16x8 af[4], bfr[4];
      #pragma unroll
      for (int fm = 0; fm < 4; ++fm) {
        const int row = wr * 64 + fm * 16 + lr;
        af[fm] = *(const bf16x8*)(smA + row * 128 + (kb ^ ((row & 7) << 4)));
      }
      #pragma unroll
      for (int fn = 0; fn < 4; ++fn) {
        const int n = wc * 64 + fn * 16 + lr;
        bfr[fn] = *(const bf16x8*)(smB + n * 128 + (kb ^ ((n & 7) << 4)));
      }
      #pragma unroll
      for (int fm = 0; fm < 4; ++fm)
        #pragma unroll
        for (int fn = 0; fn < 4; ++fn)
          acc[fm][fn] =
              __builtin_amdgcn_mfma_f32_16x16x32_bf16(af[fm], bfr[fn], acc[fm][fn], 0, 0, 0);
    }
    __syncthreads();
  }
  const int bidx = r0 >> 11;
  float hv[4], wv[4], vv[4];
  #pragma unroll
  for (int fn = 0; fn < 4; ++fn) {
    const int u = n0 + wc * 64 + fn * 16 + lr;
    hv[fn] = h2[bidx * kU + u];
    wv[fn] = Wcw[u];
    vv[fn] = Vw[u];
  }
  #pragma unroll
  for (int fm = 0; fm < 4; ++fm) {
    #pragma unroll
    for (int j = 0; j < 4; ++j) {
      const int r = r0 + wr * 64 + fm * 16 + lq * 4 + j;
      const float pcv = pc[r];
      float partial = 0.f;
      #pragma unroll
      for (int fn = 0; fn < 4; ++fn) {
        const float feat = acc[fm][fn][j] + hv[fn] + pcv * wv[fn];
        partial += tanh_fast(feat) * vv[fn];
      }
      partial += __shfl_xor(partial, 1);
      partial += __shfl_xor(partial, 2);
      partial += __shfl_xor(partial, 4);
      partial += __shfl_xor(partial, 8);
      if (lr == 0) atomicAdd(&score[r], partial);
    }
  }
}

__global__ __launch_bounds__(256) void softmax_fb_kernel(
    const float* __restrict__ score, const float* __restrict__ pc,
    float* __restrict__ attn, float* __restrict__ cov) {
  const int b = blockIdx.x, tid = threadIdx.x;
  const int lane = tid & 63, wid = tid >> 6;
  const float* s = score + (size_t)b * kS;
  float v[8];
  *(float4*)(v) = *(const float4*)(s + tid * 8);
  *(float4*)(v + 4) = *(const float4*)(s + tid * 8 + 4);
  float m = v[0];
  #pragma unroll
  for (int i = 1; i < 8; ++i) m = fmaxf(m, v[i]);
  #pragma unroll
  for (int msk = 1; msk < 64; msk <<= 1) m = fmaxf(m, __shfl_xor(m, msk));
  __shared__ float redm[4], reds[4];
  if (lane == 0) redm[wid] = m;
  __syncthreads();
  m = fmaxf(fmaxf(redm[0], redm[1]), fmaxf(redm[2], redm[3]));
  float e[8], sum = 0.f;
  #pragma unroll
  for (int i = 0; i < 8; ++i) { e[i] = __expf(v[i] - m); sum += e[i]; }
  #pragma unroll
  for (int msk = 1; msk < 64; msk <<= 1) sum += __shfl_xor(sum, msk);
  if (lane == 0) reds[wid] = sum;
  __syncthreads();
  sum = reds[0] + reds[1] + reds[2] + reds[3];
  const float inv = 1.0f / sum;
  float pv[8], a[8], c[8];
  const float* p = pc + (size_t)b * kS + tid * 8;
  *(float4*)(pv) = *(const float4*)(p);
  *(float4*)(pv + 4) = *(const float4*)(p + 4);
  #pragma unroll
  for (int i = 0; i < 8; ++i) { a[i] = e[i] * inv; c[i] = a[i] + pv[i]; }
  *(float4*)(attn + (size_t)b * kS + tid * 8) = *(float4*)(a);
  *(float4*)(attn + (size_t)b * kS + tid * 8 + 4) = *(float4*)(a + 4);
  *(float4*)(cov + (size_t)b * kS + tid * 8) = *(float4*)(c);
  *(float4*)(cov + (size_t)b * kS + tid * 8 + 4) = *(float4*)(c + 4);
}

}  // namespace

extern "C" void kernel_launch(void* const* d_in, const int* in_sizes, int n_in,
                              void* d_out, int out_size, void* d_ws, size_t ws_size,
                              hipStream_t stream) {
  (void)in_sizes; (void)n_in; (void)out_size;
  const float* dec = (const float*)d_in[0];
  const float* enc = (const float*)d_in[1];
  const float* pc  = (const float*)d_in[4];
  const float* Wsw = (const float*)d_in[5];
  const float* Wsb = (const float*)d_in[6];
  const float* Whw = (const float*)d_in[7];
  const float* Whb = (const float*)d_in[8];
  const float* Wcw = (const float*)d_in[9];
  const float* Wcb = (const float*)d_in[10];
  const float* Vw  = (const float*)d_in[11];

  float* ctx  = (float*)d_out;             // [B, D]
  float* attn = (float*)d_out + kB * kD;   // [B, S]
  float* cov  = attn + kB * kS;            // [B, S, 1]

  unsigned char* ws = (unsigned char*)d_ws;

  const size_t encT_sz  = (size_t)kB * kS * kD * 2;          // 128 MiB
  const size_t Bt_sz    = (size_t)kU * kD * 2;               // 2 MiB
  const size_t h2_sz    = (size_t)kB * kU * 4;               // 128 KiB
  const size_t sp_sz    = (size_t)16 * kB * kS * 4;          // 4 MiB
  const size_t need     = encT_sz + Bt_sz + h2_sz + sp_sz;

  hipMemsetAsync(ctx, 0, kB * kD * sizeof(float), stream);

  if (ws_size >= need) {
    unsigned char* encT = ws;
    unsigned char* Bt   = ws + encT_sz;
    float* h2     = (float*)(ws + encT_sz + Bt_sz);
    float* scorep = (float*)(ws + encT_sz + Bt_sz + h2_sz);

    convA_kernel<<<dim3((kB * kS * kD / 8) / 256), 256, 0, stream>>>(enc, encT);
    tpose2_kernel<<<dim3(kU / 32, kD / 32), dim3(32, 8), 0, stream>>>(Wsw, Bt);
    h2_kernel<<<dim3(kU / 256, kB), 256, 0, stream>>>(dec, Whw, Whb, Wsb, Wcb, h2);
    score_gemm2_kernel<<<dim3(kMT * kNT), 256, 0, stream>>>(
        encT, Bt, h2, pc, Wcw, Vw, scorep);
    softmax2_kernel<<<dim3(kB), 256, 0, stream>>>(scorep, pc, attn, cov);
    context_kernel<<<dim3(kD / 256, kS / 256, kB), 256, 0, stream>>>(enc, attn, ctx);
  } else {
    unsigned short* WsT = (unsigned short*)ws;                       // 2 MiB
    float* h2    = (float*)(ws + (size_t)2 * 1024 * 1024);           // 128 KiB
    float* score = (float*)(ws + (size_t)2 * 1024 * 1024 + 131072);  // 256 KiB
    hipMemsetAsync(score, 0, kB * kS * sizeof(float), stream);
    h2_kernel<<<dim3(kU / 256, kB), 256, 0, stream>>>(dec, Whw, Whb, Wsb, Wcb, h2);
    tpose_fb_kernel<<<dim3(kU / 32, kD / 32), dim3(32, 8), 0, stream>>>(Wsw, WsT);
    score_gemm_fb_kernel<<<dim3(kMT * kNT), 256, 0, stream>>>(
        enc, WsT, h2, pc, Wcw, Vw, score);
    softmax_fb_kernel<<<dim3(kB), 256, 0, stream>>>(score, pc, attn, cov);
    context_kernel<<<dim3(kD / 256, kS / 256, kB), 256, 0, stream>>>(enc, attn, ctx);
  }
}

// Round 4
// 310.649 us; speedup vs baseline: 1.9760x; 1.1171x over previous
//
#include <hip/hip_runtime.h>
#include <hip/hip_bf16.h>

namespace {

constexpr int kB = 32;
constexpr int kS = 2048;
constexpr int kD = 1024;
constexpr int kU = 1024;

// fast-path GEMM geometry
constexpr int BM = 256;
constexpr int BN = 256;
constexpr int BK = 64;
constexpr int kKT = kD / BK;            // 16 K-tiles
constexpr int kMT = (kB * kS) / BM;     // 256 m-tiles
constexpr int kNT = kU / BN;            // 4 n-tiles
// half-chunk = 128 rows x 64 bf16 cols = 16 KiB; tile chunk = 2 halves = 32 KiB
constexpr size_t kHalf = 16384;
constexpr size_t kTileChunk = 2 * kHalf;                 // 32 KiB
constexpr size_t kPanel = (size_t)kKT * kTileChunk;      // 512 KiB per 256-row panel

typedef __attribute__((ext_vector_type(8))) short bf16x8;
typedef __attribute__((ext_vector_type(4))) float f32x4;

__device__ __forceinline__ unsigned short f2bf(float x) {
  union { __hip_bfloat16 h; unsigned short u; } c;
  c.h = __float2bfloat16(x);
  return c.u;
}

__device__ __forceinline__ float bf2f(unsigned short u) {
  union { unsigned int i; float f; } c;
  c.i = ((unsigned int)u) << 16;
  return c.f;
}

// tanh(x) = 1 - 2/(exp(2x)+1); saturates correctly at +-large x.
__device__ __forceinline__ float tanh_fast(float x) {
  float e = __expf(2.0f * x);
  return 1.0f - 2.0f * __builtin_amdgcn_rcpf(e + 1.0f);
}

__device__ __forceinline__ void gload16(const void* g, void* l) {
  __builtin_amdgcn_global_load_lds(
      (const __attribute__((address_space(1))) void*)g,
      (__attribute__((address_space(3))) void*)l, 16, 0, 0);
}

// ---------------- shared kernels ----------------

__global__ __launch_bounds__(256) void h2_kernel(
    const float* __restrict__ dec, const float* __restrict__ Whw,
    const float* __restrict__ Whb, const float* __restrict__ Wsb,
    const float* __restrict__ Wcb, float* __restrict__ h2) {
  const int b = blockIdx.y;
  const int u = blockIdx.x * 256 + threadIdx.x;
  float acc = Whb[u] + Wsb[u] + Wcb[u];
  const float* dh = dec + b * kD;
  #pragma unroll 8
  for (int d = 0; d < kD; ++d) acc += dh[d] * Whw[(size_t)d * kU + u];
  h2[b * kU + u] = acc;
}

// ---------------- fast path ----------------

// enc fp32 [65536][1024] -> encT bf16, GEMM-ready: half-chunk (mt, kt, rh) of
// 16 KiB; inside: row-major 128 rows x 128 B with 16B XOR swizzle.
__global__ __launch_bounds__(256) void convA_kernel(
    const float* __restrict__ enc, unsigned char* __restrict__ encT) {
  const size_t e = ((size_t)blockIdx.x * 256 + threadIdx.x) * 8;
  const int r = (int)(e >> 10), d0 = (int)(e & 1023);
  float4 v0 = *(const float4*)(enc + e);
  float4 v1 = *(const float4*)(enc + e + 4);
  uint4 p;
  p.x = (unsigned)f2bf(v0.x) | ((unsigned)f2bf(v0.y) << 16);
  p.y = (unsigned)f2bf(v0.z) | ((unsigned)f2bf(v0.w) << 16);
  p.z = (unsigned)f2bf(v1.x) | ((unsigned)f2bf(v1.y) << 16);
  p.w = (unsigned)f2bf(v1.z) | ((unsigned)f2bf(v1.w) << 16);
  const int mt = r >> 8, rh = (r >> 7) & 1, row = r & 127;
  const int kt = d0 >> 6, c8 = (d0 & 63) >> 3;  // d0 multiple of 8
  unsigned char* dst = encT + (size_t)mt * kPanel + (size_t)kt * kTileChunk +
                       (size_t)rh * kHalf + row * 128 +
                       (((unsigned)c8 << 4) ^ (((unsigned)row & 7) << 4));
  *(uint4*)dst = p;
}

// Ws_w fp32 [D][U] -> bf16 B^T in the same half-chunk layout (rows = u).
__global__ __launch_bounds__(256) void tpose2_kernel(
    const float* __restrict__ W, unsigned char* __restrict__ Bt) {
  __shared__ float tile[32][33];
  const int u0 = blockIdx.x * 32, d0 = blockIdx.y * 32;
  const int tx = threadIdx.x, ty = threadIdx.y;  // 32 x 8
  #pragma unroll
  for (int i = 0; i < 4; ++i)
    tile[ty + i * 8][tx] = W[(size_t)(d0 + ty + i * 8) * kU + u0 + tx];
  __syncthreads();
  #pragma unroll
  for (int i = 0; i < 4; ++i) {
    const int u = u0 + ty + i * 8, d = d0 + tx;
    const int nt = u >> 8, gh = (u >> 7) & 1, n = u & 127;
    const int kt = d >> 6, c = d & 63;
    *(unsigned short*)(Bt + (size_t)nt * kPanel + (size_t)kt * kTileChunk +
                       (size_t)gh * kHalf + n * 128 +
                       (((((unsigned)c >> 3) << 4) ^ (((unsigned)n & 7) << 4)) +
                        (c & 7) * 2)) = f2bf(tile[tx][ty + i * 8]);
  }
}

#define MFMA_BF16(a, b, c) __builtin_amdgcn_mfma_f32_16x16x32_bf16((a), (b), (c), 0, 0, 0)

// Fused score GEMM, 256x256 tile, 8 waves, counted-vmcnt 2-phase/K-tile pipeline.
// All reads in iter t hit parity-p LDS slots, all stages hit parity-(1-p):
// provably race-free with one raw barrier per phase. vmcnt never drains to 0
// in the main loop (T3+T4); setprio around MFMA (T5); XCD-swizzled grid (T1).
__global__ __launch_bounds__(512, 2) void score_gemm3_kernel(
    const unsigned char* __restrict__ encT, const unsigned char* __restrict__ Bt,
    const float* __restrict__ h2, const float* __restrict__ pc,
    const float* __restrict__ Wcw, const float* __restrict__ Vw,
    float* __restrict__ scorep) {
  // LDS map: A slots (parity, half) at (par*2+h)*16K; B slots at 64K + (par*2+g)*16K
  __shared__ __attribute__((aligned(16))) unsigned char lds[131072];

  const int tid = threadIdx.x;
  const int lane = tid & 63;
  const int w = tid >> 6;
  const int lr = lane & 15, lq = lane >> 4;
  const int wrow = (w >> 2) * 64;        // row-64 strip within a 128-row half
  const int wcs = w & 3;                 // col-64 strip id within 256
  const int bg = wcs >> 1;               // which B half this wave reads
  const int wncol = (wcs & 1) * 64;      // row offset inside that B half

  // XCD-bijective swizzle: 1024 wgs, XCD x owns works [128x,128x+128);
  // consecutive works = 4 ntiles of one mtile -> A panel L2-reused x4.
  const int work = (blockIdx.x & 7) * 128 + (blockIdx.x >> 3);
  const int mtile = work >> 2, ntile = work & 3;

  const unsigned char* Ab = encT + (size_t)mtile * kPanel;
  const unsigned char* Bb = Bt + (size_t)ntile * kPanel;
  const int so0 = tid * 16;              // this thread's staging slice
  const int so1 = tid * 16 + 8192;

  f32x4 acc[2][4][4];
  #pragma unroll
  for (int h = 0; h < 2; ++h)
    #pragma unroll
    for (int i = 0; i < 4; ++i)
      #pragma unroll
      for (int j = 0; j < 4; ++j) acc[h][i][j] = (f32x4){0.f, 0.f, 0.f, 0.f};

  // ---- prologue: stage tile 0 into parity 0; A-H1 issued LAST ----
  {
    const unsigned char* At = Ab;
    const unsigned char* Btt = Bb;
    gload16(At + so0, lds + 0 + so0);            // A-H0
    gload16(At + so1, lds + 0 + so1);
    gload16(Btt + so0, lds + 65536 + so0);       // B-G0
    gload16(Btt + so1, lds + 65536 + so1);
    gload16(Btt + kHalf + so0, lds + 65536 + kHalf + so0);  // B-G1
    gload16(Btt + kHalf + so1, lds + 65536 + kHalf + so1);
    gload16(At + kHalf + so0, lds + kHalf + so0);           // A-H1 (last)
    gload16(At + kHalf + so1, lds + kHalf + so1);
  }

  for (int t = 0; t < kKT - 1; ++t) {
    const int p = t & 1;
    const int aP = p * 2 * (int)kHalf;               // A parity base
    const int aQ = (1 - p) * 2 * (int)kHalf;
    const int bP = 65536 + p * 2 * (int)kHalf;       // B parity base
    const int bQ = 65536 + (1 - p) * 2 * (int)kHalf;
    const unsigned char* An = Ab + (size_t)(t + 1) * kTileChunk;
    const unsigned char* Bn = Bb + (size_t)(t + 1) * kTileChunk;

    // ---- phase 1: stage {A-H0,B-G0,B-G1}(t+1) -> parity 1-p; compute h=0 ----
    gload16(An + so0, lds + aQ + so0);
    gload16(An + so1, lds + aQ + so1);
    gload16(Bn + so0, lds + bQ + so0);
    gload16(Bn + so1, lds + bQ + so1);
    gload16(Bn + (int)kHalf + so0, lds + bQ + (int)kHalf + so0);
    gload16(Bn + (int)kHalf + so1, lds + bQ + (int)kHalf + so1);
    asm volatile("s_waitcnt vmcnt(8)" ::: "memory");
    __builtin_amdgcn_s_barrier();
    __builtin_amdgcn_sched_barrier(0);

    bf16x8 bfr[4][2];
    #pragma unroll
    for (int cf = 0; cf < 4; ++cf)
      #pragma unroll
      for (int ks = 0; ks < 2; ++ks) {
        const int n = wncol + cf * 16 + lr;
        bfr[cf][ks] = *(const bf16x8*)(lds + bP + bg * (int)kHalf + n * 128 +
                                       ((ks * 64 + lq * 16) ^ ((n & 7) << 4)));
      }
    #pragma unroll
    for (int ks = 0; ks < 2; ++ks) {
      bf16x8 af[4];
      #pragma unroll
      for (int rf = 0; rf < 4; ++rf) {
        const int row = wrow + rf * 16 + lr;
        af[rf] = *(const bf16x8*)(lds + aP + row * 128 +
                                  ((ks * 64 + lq * 16) ^ ((row & 7) << 4)));
      }
      __builtin_amdgcn_s_setprio(1);
      #pragma unroll
      for (int rf = 0; rf < 4; ++rf)
        #pragma unroll
        for (int cf = 0; cf < 4; ++cf)
          acc[0][rf][cf] = MFMA_BF16(af[rf], bfr[cf][ks], acc[0][rf][cf]);
      __builtin_amdgcn_s_setprio(0);
    }

    // ---- phase 2: stage {A-H1}(t+1); compute h=1 (B-frags reused from regs) ----
    gload16(An + (int)kHalf + so0, lds + aQ + (int)kHalf + so0);
    gload16(An + (int)kHalf + so1, lds + aQ + (int)kHalf + so1);
    asm volatile("s_waitcnt vmcnt(8)" ::: "memory");
    __builtin_amdgcn_s_barrier();
    __builtin_amdgcn_sched_barrier(0);

    #pragma unroll
    for (int ks = 0; ks < 2; ++ks) {
      bf16x8 af[4];
      #pragma unroll
      for (int rf = 0; rf < 4; ++rf) {
        const int row = wrow + rf * 16 + lr;
        af[rf] = *(const bf16x8*)(lds + aP + (int)kHalf + row * 128 +
                                  ((ks * 64 + lq * 16) ^ ((row & 7) << 4)));
      }
      __builtin_amdgcn_s_setprio(1);
      #pragma unroll
      for (int rf = 0; rf < 4; ++rf)
        #pragma unroll
        for (int cf = 0; cf < 4; ++cf)
          acc[1][rf][cf] = MFMA_BF16(af[rf], bfr[cf][ks], acc[1][rf][cf]);
      __builtin_amdgcn_s_setprio(0);
    }
  }

  // ---- tail: t = 15 (parity 1), no staging; vmcnt(2) then vmcnt(0) ----
  {
    const int p = (kKT - 1) & 1;
    const int aP = p * 2 * (int)kHalf;
    const int bP = 65536 + p * 2 * (int)kHalf;

    asm volatile("s_waitcnt vmcnt(2)" ::: "memory");
    __builtin_amdgcn_s_barrier();
    __builtin_amdgcn_sched_barrier(0);

    bf16x8 bfr[4][2];
    #pragma unroll
    for (int cf = 0; cf < 4; ++cf)
      #pragma unroll
      for (int ks = 0; ks < 2; ++ks) {
        const int n = wncol + cf * 16 + lr;
        bfr[cf][ks] = *(const bf16x8*)(lds + bP + bg * (int)kHalf + n * 128 +
                                       ((ks * 64 + lq * 16) ^ ((n & 7) << 4)));
      }
    #pragma unroll
    for (int ks = 0; ks < 2; ++ks) {
      bf16x8 af[4];
      #pragma unroll
      for (int rf = 0; rf < 4; ++rf) {
        const int row = wrow + rf * 16 + lr;
        af[rf] = *(const bf16x8*)(lds + aP + row * 128 +
                                  ((ks * 64 + lq * 16) ^ ((row & 7) << 4)));
      }
      #pragma unroll
      for (int rf = 0; rf < 4; ++rf)
        #pragma unroll
        for (int cf = 0; cf < 4; ++cf)
          acc[0][rf][cf] = MFMA_BF16(af[rf], bfr[cf][ks], acc[0][rf][cf]);
    }

    asm volatile("s_waitcnt vmcnt(0)" ::: "memory");
    __builtin_amdgcn_s_barrier();
    __builtin_amdgcn_sched_barrier(0);

    #pragma unroll
    for (int ks = 0; ks < 2; ++ks) {
      bf16x8 af[4];
      #pragma unroll
      for (int rf = 0; rf < 4; ++rf) {
        const int row = wrow + rf * 16 + lr;
        af[rf] = *(const bf16x8*)(lds + aP + (int)kHalf + row * 128 +
                                  ((ks * 64 + lq * 16) ^ ((row & 7) << 4)));
      }
      #pragma unroll
      for (int rf = 0; rf < 4; ++rf)
        #pragma unroll
        for (int cf = 0; cf < 4; ++cf)
          acc[1][rf][cf] = MFMA_BF16(af[rf], bfr[cf][ks], acc[1][rf][cf]);
    }
  }

  // ---- epilogue: tanh + dot(Vw) over this wave's 64 u-cols; plane write ----
  const int bidx = mtile >> 3;  // 8 mtiles per batch row-block
  float hv[4], wv[4], vv[4];
  #pragma unroll
  for (int cf = 0; cf < 4; ++cf) {
    const int u = ntile * BN + wcs * 64 + cf * 16 + lr;
    hv[cf] = h2[bidx * kU + u];
    wv[cf] = Wcw[u];
    vv[cf] = Vw[u];
  }
  float* plane = scorep + (size_t)(ntile * 4 + wcs) * (kB * kS);
  #pragma unroll
  for (int h = 0; h < 2; ++h) {
    #pragma unroll
    for (int rf = 0; rf < 4; ++rf) {
      #pragma unroll
      for (int j = 0; j < 4; ++j) {
        const int r = mtile * BM + h * 128 + wrow + rf * 16 + lq * 4 + j;
        const float pcv = pc[r];
        float partial = 0.f;
        #pragma unroll
        for (int cf = 0; cf < 4; ++cf) {
          const float feat = acc[h][rf][cf][j] + hv[cf] + pcv * wv[cf];
          partial += tanh_fast(feat) * vv[cf];
        }
        partial += __shfl_xor(partial, 1);
        partial += __shfl_xor(partial, 2);
        partial += __shfl_xor(partial, 4);
        partial += __shfl_xor(partial, 8);
        if (lr == 0) plane[r] = partial;
      }
    }
  }
}

// softmax over S per b, summing the 16 partial-score planes; cov = attn + pc.
__global__ __launch_bounds__(256) void softmax2_kernel(
    const float* __restrict__ scorep, const float* __restrict__ pc,
    float* __restrict__ attn, float* __restrict__ cov) {
  const int b = blockIdx.x, tid = threadIdx.x;
  const int lane = tid & 63, wid = tid >> 6;
  const size_t base = (size_t)b * kS + tid * 8;
  float v[8] = {0.f, 0.f, 0.f, 0.f, 0.f, 0.f, 0.f, 0.f};
  #pragma unroll
  for (int p = 0; p < 16; ++p) {
    const float* s = scorep + (size_t)p * (kB * kS) + base;
    float4 a = *(const float4*)(s);
    float4 c = *(const float4*)(s + 4);
    v[0] += a.x; v[1] += a.y; v[2] += a.z; v[3] += a.w;
    v[4] += c.x; v[5] += c.y; v[6] += c.z; v[7] += c.w;
  }
  float m = v[0];
  #pragma unroll
  for (int i = 1; i < 8; ++i) m = fmaxf(m, v[i]);
  #pragma unroll
  for (int msk = 1; msk < 64; msk <<= 1) m = fmaxf(m, __shfl_xor(m, msk));
  __shared__ float redm[4], reds[4];
  if (lane == 0) redm[wid] = m;
  __syncthreads();
  m = fmaxf(fmaxf(redm[0], redm[1]), fmaxf(redm[2], redm[3]));
  float e[8], sum = 0.f;
  #pragma unroll
  for (int i = 0; i < 8; ++i) { e[i] = __expf(v[i] - m); sum += e[i]; }
  #pragma unroll
  for (int msk = 1; msk < 64; msk <<= 1) sum += __shfl_xor(sum, msk);
  if (lane == 0) reds[wid] = sum;
  __syncthreads();
  sum = reds[0] + reds[1] + reds[2] + reds[3];
  const float inv = 1.0f / sum;
  float pv[8], a[8], c[8];
  const float* p = pc + base;
  *(float4*)(pv) = *(const float4*)(p);
  *(float4*)(pv + 4) = *(const float4*)(p + 4);
  #pragma unroll
  for (int i = 0; i < 8; ++i) { a[i] = e[i] * inv; c[i] = a[i] + pv[i]; }
  *(float4*)(attn + base) = *(float4*)(a);
  *(float4*)(attn + base + 4) = *(float4*)(a + 4);
  *(float4*)(cov + base) = *(float4*)(c);
  *(float4*)(cov + base + 4) = *(float4*)(c + 4);
}

// context from bf16 encT: block = (kt, b); thread owns one 8-d group; no atomics.
__global__ __launch_bounds__(256) void context2_kernel(
    const unsigned char* __restrict__ encT, const float* __restrict__ attn,
    float* __restrict__ ctx) {
  const int kt = blockIdx.x;     // 16 (64-d slice)
  const int b = blockIdx.y;      // 32
  const int cg = threadIdx.x & 7;        // 16B group within 128B row
  const int rgrp = threadIdx.x >> 3;     // 32 rows per pass
  float acc8[8];
  #pragma unroll
  for (int j = 0; j < 8; ++j) acc8[j] = 0.f;
  const float* ab = attn + (size_t)b * kS;
  for (int it = 0; it < kS / 32; ++it) {
    const int s = it * 32 + rgrp;
    const int r = b * kS + s;
    const int mt = r >> 8, rh = (r >> 7) & 1, row = r & 127;
    const unsigned char* chunk = encT + (size_t)mt * kPanel +
                                 (size_t)kt * kTileChunk + (size_t)rh * kHalf;
    uint4 v = *(const uint4*)(chunk + row * 128 +
                              ((((unsigned)cg << 4) ^ (((unsigned)row & 7) << 4))));
    const float a = ab[s];
    const unsigned int* vw = (const unsigned int*)&v;
    #pragma unroll
    for (int q = 0; q < 4; ++q) {
      acc8[2 * q]     += a * bf2f((unsigned short)(vw[q] & 0xffff));
      acc8[2 * q + 1] += a * bf2f((unsigned short)(vw[q] >> 16));
    }
  }
  // reduce across the 32 row-groups via LDS
  __shared__ float red[256 * 8];
  #pragma unroll
  for (int j = 0; j < 8; ++j) red[threadIdx.x * 8 + j] = acc8[j];
  __syncthreads();
  if (rgrp < 8) {  // 64 threads: thread (rgrp=g, cg) sums group g across 4 strides? no:
  }
  // simple tree: half the rows each step
  for (int stride = 16; stride > 0; stride >>= 1) {
    if (rgrp < stride) {
      #pragma unroll
      for (int j = 0; j < 8; ++j)
        red[(rgrp * 8 + cg) * 8 + j] += red[((rgrp + stride) * 8 + cg) * 8 + j];
    }
    __syncthreads();
  }
  if (rgrp == 0) {
    #pragma unroll
    for (int j = 0; j < 8; ++j)
      ctx[(size_t)b * kD + kt * 64 + cg * 8 + j] = red[cg * 8 + j];
  }
}

// ---------------- fallback path (round-3 proven kernels, small ws) ----------------

__global__ __launch_bounds__(256) void tpose_fb_kernel(
    const float* __restrict__ W, unsigned short* __restrict__ out) {
  __shared__ float tile[32][33];
  const int u0 = blockIdx.x * 32, d0 = blockIdx.y * 32;
  const int tx = threadIdx.x, ty = threadIdx.y;
  #pragma unroll
  for (int i = 0; i < 4; ++i)
    tile[ty + i * 8][tx] = W[(size_t)(d0 + ty + i * 8) * kU + u0 + tx];
  __syncthreads();
  #pragma unroll
  for (int i = 0; i < 4; ++i)
    out[(size_t)(u0 + ty + i * 8) * kD + d0 + tx] = f2bf(tile[tx][ty + i * 8]);
}

__global__ __launch_bounds__(256, 2) void score_gemm_fb_kernel(
    const float* __restrict__ enc, const unsigned short* __restrict__ WsT,
    const float* __restrict__ h2, const float* __restrict__ pc,
    const float* __restrict__ Wcw, const float* __restrict__ Vw,
    float* __restrict__ score) {
  __shared__ __attribute__((aligned(16))) unsigned char smA[128 * 64 * 2];
  __shared__ __attribute__((aligned(16))) unsigned char smB[128 * 64 * 2];
  const int tid = threadIdx.x;
  const int lane = tid & 63;
  const int wid = tid >> 6;
  const int wr = wid >> 1, wc = wid & 1;
  const int mtile = blockIdx.x >> 3, ntile = blockIdx.x & 7;
  const int r0 = mtile * 128, n0 = ntile * 128;
  f32x4 acc[4][4];
  #pragma unroll
  for (int i = 0; i < 4; ++i)
    #pragma unroll
    for (int j = 0; j < 4; ++j) acc[i][j] = (f32x4){0.f, 0.f, 0.f, 0.f};
  const int kqA = tid & 15;
  const int rowA = tid >> 4;
  const int kcB = tid & 7;
  const int nB = tid >> 3;
  float4 aReg[8];
  uint4 bReg[4];
  #pragma unroll
  for (int i = 0; i < 8; ++i)
    aReg[i] = *(const float4*)(enc + (size_t)(r0 + rowA + 16 * i) * kD + kqA * 4);
  #pragma unroll
  for (int i = 0; i < 4; ++i)
    bReg[i] = *(const uint4*)(WsT + (size_t)(n0 + nB + 32 * i) * kD + kcB * 8);
  const int lr = lane & 15, lq = lane >> 4;
  for (int k0 = 0; k0 < kD; k0 += 64) {
    #pragma unroll
    for (int i = 0; i < 8; ++i) {
      const int row = rowA + 16 * i;
      uint2 p;
      p.x = (unsigned)f2bf(aReg[i].x) | ((unsigned)f2bf(aReg[i].y) << 16);
      p.y = (unsigned)f2bf(aReg[i].z) | ((unsigned)f2bf(aReg[i].w) << 16);
      *(uint2*)(smA + row * 128 + ((kqA * 8) ^ ((row & 7) << 4))) = p;
    }
    #pragma unroll
    for (int i = 0; i < 4; ++i) {
      const int n = nB + 32 * i;
      *(uint4*)(smB + n * 128 + ((kcB * 16) ^ ((n & 7) << 4))) = bReg[i];
    }
    __syncthreads();
    if (k0 + 64 < kD) {
      const int kn = k0 + 64;
      #pragma unroll
      for (int i = 0; i < 8; ++i)
        aReg[i] = *(const float4*)(enc + (size_t)(r0 + rowA + 16 * i) * kD + kn + kqA * 4);
      #pragma unroll
      for (int i = 0; i < 4; ++i)
        bReg[i] = *(const uint4*)(WsT + (size_t)(n0 + nB + 32 * i) * kD + kn + kcB * 8);
    }
    #pragma unroll
    for (int ks = 0; ks < 2; ++ks) {
      const int kb = ks * 64 + lq * 16;
      bf16x8 af[4], bfr[4];
      #pragma unroll
      for (int fm = 0; fm < 4; ++fm) {
        const int row = wr * 64 + fm * 16 + lr;
        af[fm] = *(const bf16x8*)(smA + row * 128 + (kb ^ ((row & 7) << 4)));
      }
      #pragma unroll
      for (int fn = 0; fn < 4; ++fn) {
        const int n = wc * 64 + fn * 16 + lr;
        bfr[fn] = *(const bf16x8*)(smB + n * 128 + (kb ^ ((n & 7) << 4)));
      }
      #pragma unroll
      for (int fm = 0; fm < 4; ++fm)
        #pragma unroll
        for (int fn = 0; fn < 4; ++fn)
          acc[fm][fn] = MFMA_BF16(af[fm], bfr[fn], acc[fm][fn]);
    }
    __syncthreads();
  }
  const int bidx = r0 >> 11;
  float hv[4], wv[4], vv[4];
  #pragma unroll
  for (int fn = 0; fn < 4; ++fn) {
    const int u = n0 + wc * 64 + fn * 16 + lr;
    hv[fn] = h2[bidx * kU + u];
    wv[fn] = Wcw[u];
    vv[fn] = Vw[u];
  }
  #pragma unroll
  for (int fm = 0; fm < 4; ++fm) {
    #pragma unroll
    for (int j = 0; j < 4; ++j) {
      const int r = r0 + wr * 64 + fm * 16 + lq * 4 + j;
      const float pcv = pc[r];
      float partial = 0.f;
      #pragma unroll
      for (int fn = 0; fn < 4; ++fn) {
        const float feat = acc[fm][fn][j] + hv[fn] + pcv * wv[fn];
        partial += tanh_fast(feat) * vv[fn];
      }
      partial += __shfl_xor(partial, 1);
      partial += __shfl_xor(partial, 2);
      partial += __shfl_xor(partial, 4);
      partial += __shfl_xor(partial, 8);
      if (lr == 0) atomicAdd(&score[r], partial);
    }
  }
}

__global__ __launch_bounds__(256) void softmax_fb_kernel(
    const float* __restrict__ score, const float* __restrict__ pc,
    float* __restrict__ attn, float* __restrict__ cov) {
  const int b = blockIdx.x, tid = threadIdx.x;
  const int lane = tid & 63, wid = tid >> 6;
  const float* s = score + (size_t)b * kS;
  float v[8];
  *(float4*)(v) = *(const float4*)(s + tid * 8);
  *(float4*)(v + 4) = *(const float4*)(s + tid * 8 + 4);
  float m = v[0];
  #pragma unroll
  for (int i = 1; i < 8; ++i) m = fmaxf(m, v[i]);
  #pragma unroll
  for (int msk = 1; msk < 64; msk <<= 1) m = fmaxf(m, __shfl_xor(m, msk));
  __shared__ float redm[4], reds[4];
  if (lane == 0) redm[wid] = m;
  __syncthreads();
  m = fmaxf(fmaxf(redm[0], redm[1]), fmaxf(redm[2], redm[3]));
  float e[8], sum = 0.f;
  #pragma unroll
  for (int i = 0; i < 8; ++i) { e[i] = __expf(v[i] - m); sum += e[i]; }
  #pragma unroll
  for (int msk = 1; msk < 64; msk <<= 1) sum += __shfl_xor(sum, msk);
  if (lane == 0) reds[wid] = sum;
  __syncthreads();
  sum = reds[0] + reds[1] + reds[2] + reds[3];
  const float inv = 1.0f / sum;
  float pv[8], a[8], c[8];
  const float* p = pc + (size_t)b * kS + tid * 8;
  *(float4*)(pv) = *(const float4*)(p);
  *(float4*)(pv + 4) = *(const float4*)(p + 4);
  #pragma unroll
  for (int i = 0; i < 8; ++i) { a[i] = e[i] * inv; c[i] = a[i] + pv[i]; }
  *(float4*)(attn + (size_t)b * kS + tid * 8) = *(float4*)(a);
  *(float4*)(attn + (size_t)b * kS + tid * 8 + 4) = *(float4*)(a + 4);
  *(float4*)(cov + (size_t)b * kS + tid * 8) = *(float4*)(c);
  *(float4*)(cov + (size_t)b * kS + tid * 8 + 4) = *(float4*)(c + 4);
}

__global__ __launch_bounds__(256) void context_fb_kernel(
    const float* __restrict__ enc, const float* __restrict__ attn,
    float* __restrict__ ctx) {
  const int b = blockIdx.z;
  const int s0 = blockIdx.y * 256;
  const int d = blockIdx.x * 256 + threadIdx.x;
  const float* e = enc + ((size_t)b * kS + s0) * kD + d;
  const float* a = attn + (size_t)b * kS + s0;
  float acc = 0.f;
  #pragma unroll 8
  for (int s = 0; s < 256; ++s) acc += a[s] * e[(size_t)s * kD];
  atomicAdd(&ctx[b * kD + d], acc);
}

}  // namespace

extern "C" void kernel_launch(void* const* d_in, const int* in_sizes, int n_in,
                              void* d_out, int out_size, void* d_ws, size_t ws_size,
                              hipStream_t stream) {
  (void)in_sizes; (void)n_in; (void)out_size;
  const float* dec = (const float*)d_in[0];
  const float* enc = (const float*)d_in[1];
  const float* pc  = (const float*)d_in[4];
  const float* Wsw = (const float*)d_in[5];
  const float* Wsb = (const float*)d_in[6];
  const float* Whw = (const float*)d_in[7];
  const float* Whb = (const float*)d_in[8];
  const float* Wcw = (const float*)d_in[9];
  const float* Wcb = (const float*)d_in[10];
  const float* Vw  = (const float*)d_in[11];

  float* ctx  = (float*)d_out;             // [B, D]
  float* attn = (float*)d_out + kB * kD;   // [B, S]
  float* cov  = attn + kB * kS;            // [B, S, 1]

  unsigned char* ws = (unsigned char*)d_ws;

  const size_t encT_sz = (size_t)kB * kS * kD * 2;   // 128 MiB
  const size_t Bt_sz   = (size_t)kU * kD * 2;        // 2 MiB
  const size_t h2_sz   = (size_t)kB * kU * 4;        // 128 KiB
  const size_t sp_sz   = (size_t)16 * kB * kS * 4;   // 4 MiB
  const size_t need    = encT_sz + Bt_sz + h2_sz + sp_sz;

  if (ws_size >= need) {
    unsigned char* encT = ws;
    unsigned char* Bt   = ws + encT_sz;
    float* h2     = (float*)(ws + encT_sz + Bt_sz);
    float* scorep = (float*)(ws + encT_sz + Bt_sz + h2_sz);

    convA_kernel<<<dim3((kB * kS * kD / 8) / 256), 256, 0, stream>>>(enc, encT);
    tpose2_kernel<<<dim3(kU / 32, kD / 32), dim3(32, 8), 0, stream>>>(Wsw, Bt);
    h2_kernel<<<dim3(kU / 256, kB), 256, 0, stream>>>(dec, Whw, Whb, Wsb, Wcb, h2);
    score_gemm3_kernel<<<dim3(kMT * kNT), 512, 0, stream>>>(
        encT, Bt, h2, pc, Wcw, Vw, scorep);
    softmax2_kernel<<<dim3(kB), 256, 0, stream>>>(scorep, pc, attn, cov);
    context2_kernel<<<dim3(kD / 64, kB), 256, 0, stream>>>(encT, attn, ctx);
  } else {
    unsigned short* WsT = (unsigned short*)ws;                       // 2 MiB
    float* h2    = (float*)(ws + (size_t)2 * 1024 * 1024);           // 128 KiB
    float* score = (float*)(ws + (size_t)2 * 1024 * 1024 + 131072);  // 256 KiB
    hipMemsetAsync(score, 0, kB * kS * sizeof(float), stream);
    hipMemsetAsync(ctx, 0, kB * kD * sizeof(float), stream);
    h2_kernel<<<dim3(kU / 256, kB), 256, 0, stream>>>(dec, Whw, Whb, Wsb, Wcb, h2);
    tpose_fb_kernel<<<dim3(kU / 32, kD / 32), dim3(32, 8), 0, stream>>>(Wsw, WsT);
    score_gemm_fb_kernel<<<dim3(4096), 256, 0, stream>>>(
        enc, WsT, h2, pc, Wcw, Vw, score);
    softmax_fb_kernel<<<dim3(kB), 256, 0, stream>>>(score, pc, attn, cov);
    context_fb_kernel<<<dim3(kD / 256, kS / 256, kB), 256, 0, stream>>>(enc, attn, ctx);
  }
}